// Round 1
// baseline (353.373 us; speedup 1.0000x reference)
//
#include <hip/hip_runtime.h>
#include <hip/hip_bf16.h>
#include <cstdint>
#include <cstddef>

// TT-dense: y = relu(x @ M + b)
// x: [4096,4096] f32, M: TT(cores r=1,16,16,16,1, dims 8^4 x 8^4), out f32 [4096,4096]
//
// Route: materialize M^T in bf16 (cheap: ~0.67 GFLOP), convert x to bf16,
// then one 4096^3 bf16 MFMA GEMM (m97 structure) with fused bias+relu.

#define GM 4096
#define GN 4096
#define GK 4096

typedef __attribute__((ext_vector_type(8))) short short8_t;
typedef __attribute__((ext_vector_type(4))) float float4_t;

__device__ __forceinline__ unsigned short f2bf(float f) {
  union { float f; uint32_t u; } v; v.f = f;
  uint32_t u = v.u;
  uint32_t r = (u + 0x7fffu + ((u >> 16) & 1u)) >> 16;  // RNE
  return (unsigned short)r;
}

// ---------------------------------------------------------------------------
// Kernel 1: merge core pairs.
// G01[a01][b01][r2] = sum_r1 core0[0,a0,b0,r1] * core1[r1,a1,b1,r2]
// G23[r2][a23][b23] = sum_r3 core2[r2,a2,b2,r3] * core3[r3,a3,b3,0]
// ---------------------------------------------------------------------------
__global__ __launch_bounds__(256) void prep_kernel(
    const float* __restrict__ c0, const float* __restrict__ c1,
    const float* __restrict__ c2, const float* __restrict__ c3,
    float* __restrict__ G01, float* __restrict__ G23) {
  int idx = blockIdx.x * 256 + threadIdx.x;  // 0..131071
  if (idx < 65536) {
    int r2 = idx & 15;
    int b01 = (idx >> 4) & 63;
    int a01 = idx >> 10;
    int a0 = a01 >> 3, a1 = a01 & 7, b0 = b01 >> 3, b1 = b01 & 7;
    float s = 0.f;
#pragma unroll
    for (int r1 = 0; r1 < 16; ++r1)
      s += c0[(a0 * 8 + b0) * 16 + r1] * c1[((r1 * 8 + a1) * 8 + b1) * 16 + r2];
    G01[idx] = s;
  } else {
    int t = idx - 65536;
    int b23 = t & 63;
    int a23 = (t >> 6) & 63;
    int r2 = t >> 12;
    int a2 = a23 >> 3, a3 = a23 & 7, b2 = b23 >> 3, b3 = b23 & 7;
    float s = 0.f;
#pragma unroll
    for (int r3 = 0; r3 < 16; ++r3)
      s += c2[((r2 * 8 + a2) * 8 + b2) * 16 + r3] * c3[(r3 * 8 + a3) * 8 + b3];
    G23[t] = s;
  }
}

// ---------------------------------------------------------------------------
// Kernel 2: Mt[n][k] (bf16, N x K row-major = M transposed so GEMM reads
// contiguous K for both operands).
// n = b01*64 + b23, k = a01*64 + a23.
// Mt[n][k] = sum_r2 G01[a01][b01][r2] * G23[r2][a23][b23]
// One block per (a01,b01); r2-slices of G23 staged through LDS (padded).
// ---------------------------------------------------------------------------
__global__ __launch_bounds__(256) void build_mt(
    const float* __restrict__ G01, const float* __restrict__ G23,
    unsigned short* __restrict__ Mt) {
  __shared__ float sl[64 * 65];  // +1 pad: conflict-free strided reads
  int a01 = blockIdx.x & 63;
  int b01 = blockIdx.x >> 6;
  float acc[16];
#pragma unroll
  for (int i = 0; i < 16; ++i) acc[i] = 0.f;

  for (int r2 = 0; r2 < 16; ++r2) {
    float g = G01[(a01 * 64 + b01) * 16 + r2];  // block-uniform (s_load)
    // stage slice G23[r2][*][*] (4096 floats), coalesced
#pragma unroll
    for (int t = 0; t < 16; ++t) {
      int e = t * 256 + threadIdx.x;
      int a23 = e >> 6, b23 = e & 63;
      sl[a23 * 65 + b23] = G23[r2 * 4096 + e];
    }
    __syncthreads();
#pragma unroll
    for (int i = 0; i < 16; ++i) {
      int e = i * 256 + threadIdx.x;
      int b23 = e >> 6, a23 = e & 63;
      acc[i] += g * sl[a23 * 65 + b23];
    }
    __syncthreads();
  }
#pragma unroll
  for (int i = 0; i < 16; ++i) {
    int e = i * 256 + threadIdx.x;
    int b23 = e >> 6, a23 = e & 63;  // consecutive lanes -> consecutive k (coalesced)
    Mt[(size_t)(b01 * 64 + b23) * GK + a01 * 64 + a23] = f2bf(acc[i]);
  }
}

// ---------------------------------------------------------------------------
// Kernel 3: x f32 -> bf16 (RNE), 8 elems/thread vectorized
// ---------------------------------------------------------------------------
__global__ __launch_bounds__(256) void convert_x(
    const float* __restrict__ x, unsigned short* __restrict__ xb) {
  int i = (blockIdx.x * 256 + threadIdx.x) * 8;
  float4_t a = *(const float4_t*)(x + i);
  float4_t b = *(const float4_t*)(x + i + 4);
  short8_t o;
  o[0] = (short)f2bf(a[0]); o[1] = (short)f2bf(a[1]);
  o[2] = (short)f2bf(a[2]); o[3] = (short)f2bf(a[3]);
  o[4] = (short)f2bf(b[0]); o[5] = (short)f2bf(b[1]);
  o[6] = (short)f2bf(b[2]); o[7] = (short)f2bf(b[3]);
  *(short8_t*)(xb + i) = o;
}

// ---------------------------------------------------------------------------
// Kernel 4: C = relu(A @ Bt^T + bias). A:[M][K] bf16, Bt:[N][K] bf16.
// m97 structure: 128x128 tile, BK=32, 4 waves (2x2, each 64x64 = 4x4 MFMA
// tiles), global_load_lds width-16 staging, 16x16x32 bf16 MFMA.
// ---------------------------------------------------------------------------
__global__ __launch_bounds__(256) void gemm_bias_relu(
    const unsigned short* __restrict__ A, const unsigned short* __restrict__ Bt,
    const float* __restrict__ bias, float* __restrict__ C) {
  __shared__ __align__(16) unsigned short As[128 * 32];  // 8 KB
  __shared__ __align__(16) unsigned short Bs[128 * 32];  // 8 KB

  int tid = threadIdx.x;
  int row0 = (int)(blockIdx.x >> 5) * 128;
  int col0 = (int)(blockIdx.x & 31) * 128;
  int wave = tid >> 6, lane = tid & 63;
  int wr = (wave >> 1) * 64, wc = (wave & 1) * 64;
  int half = lane >> 4, mrow = lane & 15;

  float4_t acc[4][4];
#pragma unroll
  for (int i = 0; i < 4; ++i)
#pragma unroll
    for (int j = 0; j < 4; ++j) acc[i][j] = (float4_t){0.f, 0.f, 0.f, 0.f};

  // Precompute per-thread staging chunk geometry. Chunk c (0..511) covers
  // LDS bytes [c*16, c*16+16) = row c>>2, k-cols (c&3)*8..+8.
  int c0i = tid, c1i = tid + 256;
  int r0 = c0i >> 2, ko0 = (c0i & 3) * 8;
  int r1 = c1i >> 2, ko1 = (c1i & 3) * 8;
  const unsigned short* A0 = A + (size_t)(row0 + r0) * GK + ko0;
  const unsigned short* A1 = A + (size_t)(row0 + r1) * GK + ko1;
  const unsigned short* B0 = Bt + (size_t)(col0 + r0) * GK + ko0;
  const unsigned short* B1 = Bt + (size_t)(col0 + r1) * GK + ko1;

  for (int k0 = 0; k0 < GK; k0 += 32) {
    __builtin_amdgcn_global_load_lds(
        (const __attribute__((address_space(1))) void*)(A0 + k0),
        (__attribute__((address_space(3))) void*)(As + c0i * 8), 16, 0, 0);
    __builtin_amdgcn_global_load_lds(
        (const __attribute__((address_space(1))) void*)(A1 + k0),
        (__attribute__((address_space(3))) void*)(As + c1i * 8), 16, 0, 0);
    __builtin_amdgcn_global_load_lds(
        (const __attribute__((address_space(1))) void*)(B0 + k0),
        (__attribute__((address_space(3))) void*)(Bs + c0i * 8), 16, 0, 0);
    __builtin_amdgcn_global_load_lds(
        (const __attribute__((address_space(1))) void*)(B1 + k0),
        (__attribute__((address_space(3))) void*)(Bs + c1i * 8), 16, 0, 0);
    __syncthreads();  // compiler emits vmcnt(0) drain before s_barrier

    short8_t af[4], bfr[4];
#pragma unroll
    for (int i = 0; i < 4; ++i)
      af[i] = *(const short8_t*)&As[(wr + i * 16 + mrow) * 32 + half * 8];
#pragma unroll
    for (int j = 0; j < 4; ++j)
      bfr[j] = *(const short8_t*)&Bs[(wc + j * 16 + mrow) * 32 + half * 8];

#pragma unroll
    for (int i = 0; i < 4; ++i)
#pragma unroll
      for (int j = 0; j < 4; ++j)
        acc[i][j] = __builtin_amdgcn_mfma_f32_16x16x32_bf16(af[i], bfr[j],
                                                            acc[i][j], 0, 0, 0);
    __syncthreads();
  }

  // Epilogue: C/D layout col=lane&15, row=(lane>>4)*4+reg. Fuse bias+relu.
#pragma unroll
  for (int j = 0; j < 4; ++j) {
    int col = col0 + wc + j * 16 + mrow;
    float bcol = bias[col];
#pragma unroll
    for (int i = 0; i < 4; ++i) {
#pragma unroll
      for (int r = 0; r < 4; ++r) {
        int row = row0 + wr + i * 16 + half * 4 + r;
        float v = acc[i][j][r] + bcol;
        C[(size_t)row * GN + col] = v > 0.f ? v : 0.f;
      }
    }
  }
}

// ---------------------------------------------------------------------------
extern "C" void kernel_launch(void* const* d_in, const int* in_sizes, int n_in,
                              void* d_out, int out_size, void* d_ws, size_t ws_size,
                              hipStream_t stream) {
  const float* x  = (const float*)d_in[0];
  const float* c0 = (const float*)d_in[1];
  const float* c1 = (const float*)d_in[2];
  const float* c2 = (const float*)d_in[3];
  const float* c3 = (const float*)d_in[4];
  const float* b  = (const float*)d_in[5];
  float* out = (float*)d_out;

  // Workspace layout: [xb 32MB][Mt 32MB][G01 256KB][G23 256KB]
  unsigned short* xb = (unsigned short*)d_ws;
  unsigned short* Mt = (unsigned short*)((char*)d_ws + (32u << 20));
  float* G01 = (float*)((char*)d_ws + (64u << 20));
  float* G23 = G01 + 65536;

  prep_kernel<<<512, 256, 0, stream>>>(c0, c1, c2, c3, G01, G23);
  build_mt<<<4096, 256, 0, stream>>>(G01, G23, Mt);
  convert_x<<<(GM * GK) / (256 * 8), 256, 0, stream>>>(x, xb);
  gemm_bias_relu<<<(GM / 128) * (GN / 128), 256, 0, stream>>>(xb, Mt, b, out);
}

// Round 2
// 310.497 us; speedup vs baseline: 1.1381x; 1.1381x over previous
//
#include <hip/hip_runtime.h>
#include <hip/hip_bf16.h>
#include <cstdint>
#include <cstddef>

// TT-dense: y = relu(x @ M + b)
// x: [4096,4096] f32, M: TT(cores r=1,16,16,16,1, dims 8^4 x 8^4), out f32.
//
// Route: materialize M^T in bf16 (~0.67 GFLOP), convert x to bf16, one
// 4096^3 bf16 MFMA GEMM (m97 structure + LDS chunk swizzle) with fused
// bias+relu.

#define GM 4096
#define GN 4096
#define GK 4096

typedef __attribute__((ext_vector_type(8))) short short8_t;
typedef __attribute__((ext_vector_type(4))) float float4_t;

__device__ __forceinline__ unsigned short f2bf(float f) {
  union { float f; uint32_t u; } v; v.f = f;
  uint32_t u = v.u;
  uint32_t r = (u + 0x7fffu + ((u >> 16) & 1u)) >> 16;  // RNE
  return (unsigned short)r;
}

// ---------------------------------------------------------------------------
// Kernel 1: merge core pairs.
// G01[a01][b01][r2] = sum_r1 core0[0,a0,b0,r1] * core1[r1,a1,b1,r2]
// G23t[r2][b23][a23] = sum_r3 core2[r2,a2,b2,r3] * core3[r3,a3,b3,0]
//   (transposed so build_mt reads are coalesced over a23)
// ---------------------------------------------------------------------------
__global__ __launch_bounds__(256) void prep_kernel(
    const float* __restrict__ c0, const float* __restrict__ c1,
    const float* __restrict__ c2, const float* __restrict__ c3,
    float* __restrict__ G01, float* __restrict__ G23t) {
  int idx = blockIdx.x * 256 + threadIdx.x;  // 0..131071
  if (idx < 65536) {
    int r2 = idx & 15;
    int b01 = (idx >> 4) & 63;
    int a01 = idx >> 10;
    int a0 = a01 >> 3, a1 = a01 & 7, b0 = b01 >> 3, b1 = b01 & 7;
    float s = 0.f;
#pragma unroll
    for (int r1 = 0; r1 < 16; ++r1)
      s += c0[(a0 * 8 + b0) * 16 + r1] * c1[((r1 * 8 + a1) * 8 + b1) * 16 + r2];
    G01[idx] = s;
  } else {
    int t = idx - 65536;        // t = r2*4096 + b23*64 + a23 (store index)
    int a23 = t & 63;
    int b23 = (t >> 6) & 63;
    int r2 = t >> 12;
    int a2 = a23 >> 3, a3 = a23 & 7, b2 = b23 >> 3, b3 = b23 & 7;
    float s = 0.f;
#pragma unroll
    for (int r3 = 0; r3 < 16; ++r3)
      s += c2[((r2 * 8 + a2) * 8 + b2) * 16 + r3] * c3[(r3 * 8 + a3) * 8 + b3];
    G23t[t] = s;  // coalesced store
  }
}

// ---------------------------------------------------------------------------
// Kernel 2 (v2): Mt[n][k] bf16, n = b01*64+b23, k = a01*64+a23.
// Mt[n][k] = sum_r2 G01[a01][b01][r2] * G23t[r2][b23][a23]
// Barrier-free, LDS-free: block = (a01, group of 4 b01); per-thread 4x16
// f32 accumulators; G23t reads coalesced + L2-resident (256 KB).
// ---------------------------------------------------------------------------
__global__ __launch_bounds__(256) void build_mt(
    const float* __restrict__ G01, const float* __restrict__ G23t,
    unsigned short* __restrict__ Mt) {
  int a01 = blockIdx.x >> 4;
  int g = blockIdx.x & 15;      // b01 = g*4 + j
  int tid = threadIdx.x;

  float acc[4][16];
#pragma unroll
  for (int j = 0; j < 4; ++j)
#pragma unroll
    for (int i = 0; i < 16; ++i) acc[j][i] = 0.f;

  for (int r2 = 0; r2 < 16; ++r2) {
    float gv[4];
#pragma unroll
    for (int j = 0; j < 4; ++j)
      gv[j] = G01[(a01 * 64 + g * 4 + j) * 16 + r2];  // block-uniform
    float v[16];
#pragma unroll
    for (int i = 0; i < 16; ++i)
      v[i] = G23t[r2 * 4096 + i * 256 + tid];          // coalesced, L2-hot
#pragma unroll
    for (int i = 0; i < 16; ++i)
#pragma unroll
      for (int j = 0; j < 4; ++j) acc[j][i] += gv[j] * v[i];
  }

#pragma unroll
  for (int j = 0; j < 4; ++j) {
#pragma unroll
    for (int i = 0; i < 16; ++i) {
      int e = i * 256 + tid;
      int b23 = e >> 6, a23 = e & 63;   // wave = one row, 64 consecutive k
      Mt[(size_t)((g * 4 + j) * 64 + b23) * GK + a01 * 64 + a23] =
          f2bf(acc[j][i]);
    }
  }
}

// ---------------------------------------------------------------------------
// Kernel 3: x f32 -> bf16 (RNE), 8 elems/thread vectorized
// ---------------------------------------------------------------------------
__global__ __launch_bounds__(256) void convert_x(
    const float* __restrict__ x, unsigned short* __restrict__ xb) {
  int i = (blockIdx.x * 256 + threadIdx.x) * 8;
  float4_t a = *(const float4_t*)(x + i);
  float4_t b = *(const float4_t*)(x + i + 4);
  short8_t o;
  o[0] = (short)f2bf(a[0]); o[1] = (short)f2bf(a[1]);
  o[2] = (short)f2bf(a[2]); o[3] = (short)f2bf(a[3]);
  o[4] = (short)f2bf(b[0]); o[5] = (short)f2bf(b[1]);
  o[6] = (short)f2bf(b[2]); o[7] = (short)f2bf(b[3]);
  *(short8_t*)(xb + i) = o;
}

// ---------------------------------------------------------------------------
// Kernel 4: C = relu(A @ Bt^T + bias). A:[M][K] bf16, Bt:[N][K] bf16.
// m97 structure: 128x128 tile, BK=32, 4 waves (2x2), global_load_lds
// width-16 staging, 16x16x32 bf16 MFMA.
//
// LDS chunk swizzle (bank-conflict fix): LDS row r holds its four 16B
// k-chunks in permuted order; chunk at position p of row r contains k-span
// h*8..h*8+8 with h = (p - (r>>1)) & 3. Staging keeps the lane-contiguous
// LDS destination required by global_load_lds (chunk c -> As + c*16B) and
// permutes the *global* source address instead. Fragment read for k-half
// `half` of row r uses position (half + (r>>1)) & 3 -> 16 consecutive rows
// cover all 8 bank groups (was 2 of 8 -> ~8-way conflict).
// ---------------------------------------------------------------------------
__global__ __launch_bounds__(256) void gemm_bias_relu(
    const unsigned short* __restrict__ A, const unsigned short* __restrict__ Bt,
    const float* __restrict__ bias, float* __restrict__ C) {
  __shared__ __align__(16) unsigned short As[128 * 32];  // 8 KB
  __shared__ __align__(16) unsigned short Bs[128 * 32];  // 8 KB

  int tid = threadIdx.x;
  int row0 = (int)(blockIdx.x >> 5) * 128;
  int col0 = (int)(blockIdx.x & 31) * 128;
  int wave = tid >> 6, lane = tid & 63;
  int wr = (wave >> 1) * 64, wc = (wave & 1) * 64;
  int half = lane >> 4, mrow = lane & 15;

  float4_t acc[4][4];
#pragma unroll
  for (int i = 0; i < 4; ++i)
#pragma unroll
    for (int j = 0; j < 4; ++j) acc[i][j] = (float4_t){0.f, 0.f, 0.f, 0.f};

  // Staging geometry: thread owns LDS chunks c0i=tid, c1i=tid+256.
  // LDS chunk c = row (c>>2), position (c&3); source k-half h = (p-(r>>1))&3.
  int c0i = tid, c1i = tid + 256;
  int r0 = c0i >> 2, h0 = ((c0i & 3) - (r0 >> 1)) & 3;
  int r1 = c1i >> 2, h1 = ((c1i & 3) - (r1 >> 1)) & 3;
  const unsigned short* A0 = A + (size_t)(row0 + r0) * GK + h0 * 8;
  const unsigned short* A1 = A + (size_t)(row0 + r1) * GK + h1 * 8;
  const unsigned short* B0 = Bt + (size_t)(col0 + r0) * GK + h0 * 8;
  const unsigned short* B1 = Bt + (size_t)(col0 + r1) * GK + h1 * 8;

  // Precompute swizzled fragment offsets (loop-invariant).
  int aoff[4], boff[4];
#pragma unroll
  for (int i = 0; i < 4; ++i) {
    int rA = wr + i * 16 + mrow;
    aoff[i] = rA * 32 + (((half + (rA >> 1)) & 3) * 8);
    int rB = wc + i * 16 + mrow;
    boff[i] = rB * 32 + (((half + (rB >> 1)) & 3) * 8);
  }

  for (int k0 = 0; k0 < GK; k0 += 32) {
    __builtin_amdgcn_global_load_lds(
        (const __attribute__((address_space(1))) void*)(A0 + k0),
        (__attribute__((address_space(3))) void*)(As + c0i * 8), 16, 0, 0);
    __builtin_amdgcn_global_load_lds(
        (const __attribute__((address_space(1))) void*)(A1 + k0),
        (__attribute__((address_space(3))) void*)(As + c1i * 8), 16, 0, 0);
    __builtin_amdgcn_global_load_lds(
        (const __attribute__((address_space(1))) void*)(B0 + k0),
        (__attribute__((address_space(3))) void*)(Bs + c0i * 8), 16, 0, 0);
    __builtin_amdgcn_global_load_lds(
        (const __attribute__((address_space(1))) void*)(B1 + k0),
        (__attribute__((address_space(3))) void*)(Bs + c1i * 8), 16, 0, 0);
    __syncthreads();

    short8_t af[4], bfr[4];
#pragma unroll
    for (int i = 0; i < 4; ++i) af[i] = *(const short8_t*)&As[aoff[i]];
#pragma unroll
    for (int j = 0; j < 4; ++j) bfr[j] = *(const short8_t*)&Bs[boff[j]];

#pragma unroll
    for (int i = 0; i < 4; ++i)
#pragma unroll
      for (int j = 0; j < 4; ++j)
        acc[i][j] = __builtin_amdgcn_mfma_f32_16x16x32_bf16(af[i], bfr[j],
                                                            acc[i][j], 0, 0, 0);
    __syncthreads();
  }

  // Epilogue: C/D layout col=lane&15, row=(lane>>4)*4+reg. Fuse bias+relu.
#pragma unroll
  for (int j = 0; j < 4; ++j) {
    int col = col0 + wc + j * 16 + mrow;
    float bcol = bias[col];
#pragma unroll
    for (int i = 0; i < 4; ++i) {
#pragma unroll
      for (int r = 0; r < 4; ++r) {
        int row = row0 + wr + i * 16 + half * 4 + r;
        float v = acc[i][j][r] + bcol;
        C[(size_t)row * GN + col] = v > 0.f ? v : 0.f;
      }
    }
  }
}

// ---------------------------------------------------------------------------
extern "C" void kernel_launch(void* const* d_in, const int* in_sizes, int n_in,
                              void* d_out, int out_size, void* d_ws, size_t ws_size,
                              hipStream_t stream) {
  const float* x  = (const float*)d_in[0];
  const float* c0 = (const float*)d_in[1];
  const float* c1 = (const float*)d_in[2];
  const float* c2 = (const float*)d_in[3];
  const float* c3 = (const float*)d_in[4];
  const float* b  = (const float*)d_in[5];
  float* out = (float*)d_out;

  // Workspace layout: [xb 32MB][Mt 32MB][G01 256KB][G23t 256KB]
  unsigned short* xb = (unsigned short*)d_ws;
  unsigned short* Mt = (unsigned short*)((char*)d_ws + (32u << 20));
  float* G01 = (float*)((char*)d_ws + (64u << 20));
  float* G23t = G01 + 65536;

  prep_kernel<<<512, 256, 0, stream>>>(c0, c1, c2, c3, G01, G23t);
  build_mt<<<1024, 256, 0, stream>>>(G01, G23t, Mt);
  convert_x<<<(GM * GK) / (256 * 8), 256, 0, stream>>>(x, xb);
  gemm_bias_relu<<<(GM / 128) * (GN / 128), 256, 0, stream>>>(xb, Mt, b, out);
}